// Round 10
// baseline (196.568 us; speedup 1.0000x reference)
//
#include <hip/hip_runtime.h>
#include <hip/hip_bf16.h>

#define D 64
#define BSHIFT 6
#define BW (1 << BSHIFT)          // bucket width: 64 destination nodes
#define MAXB 2048                 // max buckets (LDS arrays in bin)
#define CAP 4096                  // max edges sorted per LDS round (16 KB)
#define STRIDE 2048               // fixed tmp slots per bucket (mean 640)
#define GT 256                    // gather block threads (4 waves)
#define SMEM_BYTES 27648          // msg_bin union: msg(27648) >= bin(24576)
#define WFRAG_SHORTS (24 * 64 * 8)   // out-MLP fragment-ordered weights (24 KB)

typedef __attribute__((ext_vector_type(8))) short bf16x8;   // 8 bf16 in 4 VGPRs
typedef __attribute__((ext_vector_type(4))) float f32x4;

__device__ __forceinline__ short f2bf(float f) {
    __hip_bfloat16 h = __float2bfloat16(f);
    return *reinterpret_cast<short*>(&h);
}

// ---------------------------------------------------------------------------
// Merged K1: blocks [0,nmsg) = message MLP (verified R6 msg body);
// [nmsg, nmsg+nbin) = edge binning (verified R6 bin body);
// block nmsg+nbin = out-weight fragment prep (24 KB, fragment-ordered bf16).
// ---------------------------------------------------------------------------
__global__ __launch_bounds__(256) void msg_bin_kernel(
    const float* __restrict__ x,
    const float* __restrict__ w1, const float* __restrict__ b1,
    const float* __restrict__ w2, const float* __restrict__ b2,
    __hip_bfloat16* __restrict__ m, int n_nodes,
    const int* __restrict__ row, const int* __restrict__ col,
    int* __restrict__ gcur, unsigned int* __restrict__ tmp,
    int n_edges, int nbuckets, int chunk, int nmsg, int nbin,
    const float* __restrict__ ow1, const float* __restrict__ ow2,
    short* __restrict__ wfrag)
{
    __shared__ __align__(16) char smem[SMEM_BYTES];

    if ((int)blockIdx.x >= nmsg + nbin) {
        // ------------- prep branch: out weights -> fragment order -------------
        const int t = threadIdx.x;
        for (int idx = t; idx < 24 * 64; idx += 256) {
            const int f = idx >> 6;          // fragment id 0..23
            const int l = idx & 63;          // lane
            const int mrL = l & 15, quadL = l >> 4;
            const float* w; int ks, nb;
            if (f < 16) { ks = f >> 2;        nb = f & 3;        w = ow1; }
            else        { ks = (f - 16) >> 2; nb = (f - 16) & 3; w = ow2; }
            short* dst = wfrag + (size_t)idx * 8;
#pragma unroll
            for (int j = 0; j < 8; ++j) {
                const int k = ks * 32 + quadL * 8 + j;
                dst[j] = f2bf(w[k * D + nb * 16 + mrL]);
            }
        }
        return;
    }

    if ((int)blockIdx.x >= nmsg) {
        // ---------------- bin branch (R6 bin_kernel body) ----------------
        int* hist = (int*)smem;            // MAXB*4 = 8192
        int* base = hist + MAXB;           // 8192
        int* lcur = base + MAXB;           // 8192  (total 24576 <= SMEM)
        const int t = threadIdx.x;
        const int bb = blockIdx.x - nmsg;
        const int e0 = bb * chunk;
        const int e1 = min(e0 + chunk, n_edges);

        for (int i = t; i < nbuckets; i += 256) hist[i] = 0;
        __syncthreads();
        for (int e = e0 + t; e < e1; e += 256)
            atomicAdd(&hist[col[e] >> BSHIFT], 1);
        __syncthreads();
        for (int i = t; i < nbuckets; i += 256) {
            base[i] = hist[i] ? atomicAdd(&gcur[i], hist[i]) : 0;
            lcur[i] = 0;
        }
        __syncthreads();
        for (int e = e0 + t; e < e1; e += 256) {
            int c = col[e];
            int b = c >> BSHIFT;
            int loc = base[b] + atomicAdd(&lcur[b], 1);
            if (loc < STRIDE) {   // overflow clamp (memory safety)
                unsigned int val = ((unsigned int)(c & (BW - 1)) << 17)
                                 | (unsigned int)row[e];
                tmp[(size_t)b * STRIDE + loc] = val;
            }
        }
        return;
    }

    // ---------------- msg branch (R6 msg_kernel body) ----------------
    __hip_bfloat16* sHb = (__hip_bfloat16*)smem;        // 4*16*72*2 = 9216
    short* sW1 = (short*)(smem + 9216);                 // 64*72*2   = 9216
    short* sW2 = (short*)(smem + 18432);                // 64*72*2   = 9216

    const int tid  = threadIdx.x;
    const int lane = tid & 63;
    const int wslot = tid >> 6;
    const int mr   = lane & 15;
    const int quad = lane >> 4;

    for (int i = tid; i < 1024; i += 256) {
        const int r = i >> 4, c = (i & 15) * 4;
        float4 f = *(const float4*)&w1[i * 4];
        short* d = &sW1[r * 72 + c];
        d[0] = f2bf(f.x); d[1] = f2bf(f.y); d[2] = f2bf(f.z); d[3] = f2bf(f.w);
        float4 g = *(const float4*)&w2[i * 4];
        short* e = &sW2[r * 72 + c];
        e[0] = f2bf(g.x); e[1] = f2bf(g.y); e[2] = f2bf(g.z); e[3] = f2bf(g.w);
    }
    __syncthreads();

    bf16x8 w1f[2][4], w2f[2][4];
    float  b1v[4], b2v[4];
#pragma unroll
    for (int ks = 0; ks < 2; ++ks)
#pragma unroll
        for (int nb = 0; nb < 4; ++nb) {
            bf16x8 f1, f2;
#pragma unroll
            for (int j = 0; j < 8; ++j) {
                int k = ks * 32 + quad * 8 + j;
                f1[j] = sW1[k * 72 + nb * 16 + mr];
                f2[j] = sW2[k * 72 + nb * 16 + mr];
            }
            w1f[ks][nb] = f1;
            w2f[ks][nb] = f2;
        }
#pragma unroll
    for (int nb = 0; nb < 4; ++nb) {
        b1v[nb] = b1[nb * 16 + mr];
        b2v[nb] = b2[nb * 16 + mr];
    }

    __hip_bfloat16* Hw = sHb + wslot * (16 * 72);
    const int wid    = (blockIdx.x * 256 + threadIdx.x) >> 6;
    const int nwaves = nmsg * 4;
    const int ntiles = (n_nodes + 15) >> 4;

    for (int t = wid; t < ntiles; t += nwaves) {
        const int v0 = t * 16;
        int vr = v0 + mr;
        if (vr >= n_nodes) vr = n_nodes - 1;

        bf16x8 a[2];
#pragma unroll
        for (int ks = 0; ks < 2; ++ks) {
            const float* p = x + (size_t)vr * D + ks * 32 + quad * 8;
            float4 lo = *(const float4*)p;
            float4 hi = *(const float4*)(p + 4);
            bf16x8 f;
            f[0] = f2bf(lo.x); f[1] = f2bf(lo.y); f[2] = f2bf(lo.z); f[3] = f2bf(lo.w);
            f[4] = f2bf(hi.x); f[5] = f2bf(hi.y); f[6] = f2bf(hi.z); f[7] = f2bf(hi.w);
            a[ks] = f;
        }

#pragma unroll
        for (int nb = 0; nb < 4; ++nb) {
            f32x4 acc = {0.f, 0.f, 0.f, 0.f};
            acc = __builtin_amdgcn_mfma_f32_16x16x32_bf16(a[0], w1f[0][nb], acc, 0, 0, 0);
            acc = __builtin_amdgcn_mfma_f32_16x16x32_bf16(a[1], w1f[1][nb], acc, 0, 0, 0);
#pragma unroll
            for (int r = 0; r < 4; ++r) {
                float hv = fmaxf(acc[r] + b1v[nb], 0.f);
                Hw[(quad * 4 + r) * 72 + nb * 16 + mr] = __float2bfloat16(hv);
            }
        }

        bf16x8 h[2];
#pragma unroll
        for (int ks = 0; ks < 2; ++ks)
            h[ks] = *(const bf16x8*)&Hw[mr * 72 + ks * 32 + quad * 8];

#pragma unroll
        for (int nb = 0; nb < 4; ++nb) {
            f32x4 acc = {0.f, 0.f, 0.f, 0.f};
            acc = __builtin_amdgcn_mfma_f32_16x16x32_bf16(h[0], w2f[0][nb], acc, 0, 0, 0);
            acc = __builtin_amdgcn_mfma_f32_16x16x32_bf16(h[1], w2f[1][nb], acc, 0, 0, 0);
#pragma unroll
            for (int r = 0; r < 4; ++r)
                Hw[(quad * 4 + r) * 72 + nb * 16 + mr] =
                    __float2bfloat16(acc[r] + b2v[nb]);
        }

#pragma unroll
        for (int s = 0; s < 2; ++s) {
            const int rrow = s * 8 + (lane >> 3);
            const int cblk = (lane & 7) * 8;
            bf16x8 val = *(const bf16x8*)&Hw[rrow * 72 + cblk];
            const int vrow = v0 + rrow;
            if (vrow < n_nodes)
                *(bf16x8*)&m[(size_t)vrow * D + cblk] = val;
        }
    }
}

// ---------------------------------------------------------------------------
// K2: fused sort + gather + out-MLP.  Gather phase = verified R8 structure.
// Epilogue: acc -> bf16 LDS tile aggT (reusing sorted buffer), each wave runs
// the out-MLP for one 16-node tile (weights from fragment-ordered wfrag).
// Eliminates the out_kernel launch and the agg HBM round-trip.
// ---------------------------------------------------------------------------
__global__ __launch_bounds__(GT) void bucket_gather_out_kernel(
    const int* __restrict__ gcur, const unsigned int* __restrict__ tmp,
    const __hip_bfloat16* __restrict__ m, const float* __restrict__ x,
    const short* __restrict__ wfrag,
    const float* __restrict__ ob1, const float* __restrict__ ob2,
    float* __restrict__ out, int n_nodes, int nbuckets)
{
    __shared__ __align__(16) char smem[18432];   // sorted(16K) -> aggT(9216)+sH(9216)
    __shared__ int cnt[BW], off[BW], cur[BW];
    unsigned int* sorted = (unsigned int*)smem;

    const int b    = blockIdx.x;
    const int t    = threadIdx.x;
    const int lane = t & 63;
    const int wv   = t >> 6;               // 0..3
    const int vbase = b << BSHIFT;
    const unsigned int* gtmp = tmp + (size_t)b * STRIDE;

    const int total = min(gcur[b], STRIDE);

    float acc[16];                         // wave wv owns nodes wv + 4*i
#pragma unroll
    for (int i = 0; i < 16; ++i) acc[i] = 0.f;

    for (int r0 = 0; r0 < total; r0 += CAP) {
        const int r1 = min(r0 + CAP, total);

        if (t < BW) cnt[t] = 0;
        __syncthreads();

        for (int i = r0 + t; i < r1; i += GT)
            atomicAdd(&cnt[gtmp[i] >> 17], 1);
        __syncthreads();

        // 64-bin exclusive scan by wave 0: 1 bin/lane, 6 shfl_up steps.
        if (wv == 0) {
            int a0 = cnt[lane];
            int s0 = a0;
#pragma unroll
            for (int d = 1; d < 64; d <<= 1) {
                int u0 = __shfl_up(s0, d, 64);
                if (lane >= d) s0 += u0;
            }
            const int e0 = s0 - a0;                // exclusive prefix
            off[lane] = e0;
            cur[lane] = e0;
        }
        __syncthreads();

        for (int i = r0 + t; i < r1; i += GT) {
            unsigned int u = gtmp[i];
            int pos = atomicAdd(&cur[u >> 17], 1);
            sorted[pos] = u;
        }
        __syncthreads();

#pragma unroll
        for (int i = 0; i < 16; ++i) {
            const int n  = wv + (i << 2);
            const int o0 = off[n];
            const int c  = cnt[n];
            float s = 0.f;
            for (int cs = 0; cs < c; cs += 64) {
                const int k = min(64, c - cs);
                unsigned int pv = 0;
                if (lane < k) pv = sorted[o0 + cs + lane];

                int j = 0;
                for (; j + 8 <= k; j += 8) {
                    unsigned int u[8];
                    float v[8];
#pragma unroll
                    for (int q = 0; q < 8; ++q)
                        u[q] = __builtin_amdgcn_readlane(pv, j + q);
#pragma unroll
                    for (int q = 0; q < 8; ++q)
                        v[q] = (float)m[(size_t)(u[q] & 0x1FFFFu) * D + lane];
#pragma unroll
                    for (int q = 0; q < 8; ++q)
                        s += v[q];
                }
                for (; j < k; ++j) {
                    unsigned int u = __builtin_amdgcn_readlane(pv, j);
                    s += (float)m[(size_t)(u & 0x1FFFFu) * D + lane];
                }
            }
            acc[i] += s;
        }
        __syncthreads();   // sorted reads done before reuse / next round
    }

    // ---- epilogue: out-MLP for this bucket's 64 nodes ----
    __hip_bfloat16* aggT = (__hip_bfloat16*)smem;            // [64][72] bf16
    __hip_bfloat16* sH   = (__hip_bfloat16*)(smem + 9216);   // [4][16*72] bf16

#pragma unroll
    for (int i = 0; i < 16; ++i)
        aggT[(wv + (i << 2)) * 72 + lane] = __float2bfloat16(acc[i]);
    __syncthreads();

    const int mr   = lane & 15;
    const int quad = lane >> 4;
    const int v0   = vbase + wv * 16;      // wave wv owns one 16-node tile
    int vr = v0 + mr;
    if (vr >= n_nodes) vr = n_nodes - 1;

    bf16x8 a[4];
#pragma unroll
    for (int ks = 0; ks < 2; ++ks) {
        const float* p = x + (size_t)vr * D + ks * 32 + quad * 8;
        float4 lo = *(const float4*)p;
        float4 hi = *(const float4*)(p + 4);
        bf16x8 f;
        f[0] = f2bf(lo.x); f[1] = f2bf(lo.y); f[2] = f2bf(lo.z); f[3] = f2bf(lo.w);
        f[4] = f2bf(hi.x); f[5] = f2bf(hi.y); f[6] = f2bf(hi.z); f[7] = f2bf(hi.w);
        a[ks] = f;
    }
#pragma unroll
    for (int ks = 2; ks < 4; ++ks)
        a[ks] = *(const bf16x8*)&aggT[(wv * 16 + mr) * 72 + (ks - 2) * 32 + quad * 8];

    float b1v[4], b2v[4];
#pragma unroll
    for (int nb = 0; nb < 4; ++nb) {
        b1v[nb] = ob1[nb * 16 + mr];
        b2v[nb] = ob2[nb * 16 + mr];
    }

    __hip_bfloat16* Hw = sH + wv * (16 * 72);
#pragma unroll
    for (int nb = 0; nb < 4; ++nb) {
        f32x4 c4 = {0.f, 0.f, 0.f, 0.f};
#pragma unroll
        for (int ks = 0; ks < 4; ++ks) {
            bf16x8 wf = *(const bf16x8*)&wfrag[((size_t)(ks * 4 + nb) * 64 + lane) * 8];
            c4 = __builtin_amdgcn_mfma_f32_16x16x32_bf16(a[ks], wf, c4, 0, 0, 0);
        }
#pragma unroll
        for (int r = 0; r < 4; ++r) {
            float hv = fmaxf(c4[r] + b1v[nb], 0.f);
            Hw[(quad * 4 + r) * 72 + nb * 16 + mr] = __float2bfloat16(hv);
        }
    }

    bf16x8 h[2];
#pragma unroll
    for (int ks = 0; ks < 2; ++ks)
        h[ks] = *(const bf16x8*)&Hw[mr * 72 + ks * 32 + quad * 8];

#pragma unroll
    for (int nb = 0; nb < 4; ++nb) {
        f32x4 c4 = {0.f, 0.f, 0.f, 0.f};
#pragma unroll
        for (int ks = 0; ks < 2; ++ks) {
            bf16x8 wf = *(const bf16x8*)&wfrag[((size_t)(16 + ks * 4 + nb) * 64 + lane) * 8];
            c4 = __builtin_amdgcn_mfma_f32_16x16x32_bf16(h[ks], wf, c4, 0, 0, 0);
        }
#pragma unroll
        for (int r = 0; r < 4; ++r) {
            const int vrow = v0 + quad * 4 + r;
            if (vrow < n_nodes)
                out[(size_t)vrow * D + nb * 16 + mr] = c4[r] + b2v[nb];
        }
    }
}

// ---------------------------------------------------------------------------
// Fallback path (ws too small / shape out of range).
// ---------------------------------------------------------------------------
__global__ __launch_bounds__(256) void scatter_kernel(
    const int* __restrict__ row, const int* __restrict__ col,
    const __hip_bfloat16* __restrict__ m, float* __restrict__ aggf, int n_edges)
{
    const int lane = threadIdx.x & 63;
    const int wid  = (blockIdx.x * blockDim.x + threadIdx.x) >> 6;
    const int base = wid * 64;
    if (base >= n_edges) return;
    const int cnt = min(64, n_edges - base);

    int my_r = 0, my_c = 0;
    if (lane < cnt) { my_r = row[base + lane]; my_c = col[base + lane]; }

    for (int j = 0; j < cnt; ++j) {
        int r = __builtin_amdgcn_readlane(my_r, j);
        int c = __builtin_amdgcn_readlane(my_c, j);
        float v = (float)m[(size_t)r * D + lane];
        atomicAdd(&aggf[(size_t)c * D + lane], v);
    }
}

__global__ __launch_bounds__(256) void cvt_kernel(
    const float* __restrict__ aggf, __hip_bfloat16* __restrict__ agg, int n)
{
    int i = blockIdx.x * blockDim.x + threadIdx.x;
    if (i < n) agg[i] = __float2bfloat16(aggf[i]);
}

// ---------------------------------------------------------------------------
// K3 (fallback only): output MLP via MFMA.
// ---------------------------------------------------------------------------
__global__ __launch_bounds__(256) void out_kernel(
    const float* __restrict__ x, const __hip_bfloat16* __restrict__ agg,
    const float* __restrict__ w1, const float* __restrict__ b1,
    const float* __restrict__ w2, const float* __restrict__ b2,
    float* __restrict__ out, int n_nodes)
{
    __shared__ __align__(16) __hip_bfloat16 sH[4][16 * 72];
    __shared__ short sW1[128 * 72];     // 18432 B
    __shared__ short sW2[64 * 72];      //  9216 B

    const int tid  = threadIdx.x;
    const int lane = tid & 63;
    const int wslot = tid >> 6;
    const int mr   = lane & 15;
    const int quad = lane >> 4;

    for (int i = tid; i < 2048; i += 256) {
        const int r = i >> 4, c = (i & 15) * 4;
        float4 f = *(const float4*)&w1[i * 4];
        short* d = &sW1[r * 72 + c];
        d[0] = f2bf(f.x); d[1] = f2bf(f.y); d[2] = f2bf(f.z); d[3] = f2bf(f.w);
    }
    for (int i = tid; i < 1024; i += 256) {
        const int r = i >> 4, c = (i & 15) * 4;
        float4 g = *(const float4*)&w2[i * 4];
        short* e = &sW2[r * 72 + c];
        e[0] = f2bf(g.x); e[1] = f2bf(g.y); e[2] = f2bf(g.z); e[3] = f2bf(g.w);
    }
    __syncthreads();

    bf16x8 w1f[4][4], w2f[2][4];
    float  b1v[4], b2v[4];
#pragma unroll
    for (int ks = 0; ks < 4; ++ks)
#pragma unroll
        for (int nb = 0; nb < 4; ++nb) {
            bf16x8 f;
#pragma unroll
            for (int j = 0; j < 8; ++j) {
                int k = ks * 32 + quad * 8 + j;
                f[j] = sW1[k * 72 + nb * 16 + mr];
            }
            w1f[ks][nb] = f;
        }
#pragma unroll
    for (int ks = 0; ks < 2; ++ks)
#pragma unroll
        for (int nb = 0; nb < 4; ++nb) {
            bf16x8 f;
#pragma unroll
            for (int j = 0; j < 8; ++j) {
                int k = ks * 32 + quad * 8 + j;
                f[j] = sW2[k * 72 + nb * 16 + mr];
            }
            w2f[ks][nb] = f;
        }
#pragma unroll
    for (int nb = 0; nb < 4; ++nb) {
        b1v[nb] = b1[nb * 16 + mr];
        b2v[nb] = b2[nb * 16 + mr];
    }

    __hip_bfloat16* Hw = sH[wslot];
    const int wid    = (blockIdx.x * blockDim.x + threadIdx.x) >> 6;
    const int nwaves = (gridDim.x * blockDim.x) >> 6;
    const int ntiles = (n_nodes + 15) >> 4;

    for (int t = wid; t < ntiles; t += nwaves) {
        const int v0 = t * 16;
        int vr = v0 + mr;
        if (vr >= n_nodes) vr = n_nodes - 1;

        bf16x8 a[4];
#pragma unroll
        for (int ks = 0; ks < 2; ++ks) {
            const float* p = x + (size_t)vr * D + ks * 32 + quad * 8;
            float4 lo = *(const float4*)p;
            float4 hi = *(const float4*)(p + 4);
            bf16x8 f;
            f[0] = f2bf(lo.x); f[1] = f2bf(lo.y); f[2] = f2bf(lo.z); f[3] = f2bf(lo.w);
            f[4] = f2bf(hi.x); f[5] = f2bf(hi.y); f[6] = f2bf(hi.z); f[7] = f2bf(hi.w);
            a[ks] = f;
        }
#pragma unroll
        for (int ks = 2; ks < 4; ++ks)
            a[ks] = *(const bf16x8*)&agg[(size_t)vr * D + (ks - 2) * 32 + quad * 8];

#pragma unroll
        for (int nb = 0; nb < 4; ++nb) {
            f32x4 acc = {0.f, 0.f, 0.f, 0.f};
#pragma unroll
            for (int ks = 0; ks < 4; ++ks)
                acc = __builtin_amdgcn_mfma_f32_16x16x32_bf16(a[ks], w1f[ks][nb], acc, 0, 0, 0);
#pragma unroll
            for (int r = 0; r < 4; ++r) {
                float hv = fmaxf(acc[r] + b1v[nb], 0.f);
                Hw[(quad * 4 + r) * 72 + nb * 16 + mr] = __float2bfloat16(hv);
            }
        }

        bf16x8 h[2];
#pragma unroll
        for (int ks = 0; ks < 2; ++ks)
            h[ks] = *(const bf16x8*)&Hw[mr * 72 + ks * 32 + quad * 8];

#pragma unroll
        for (int nb = 0; nb < 4; ++nb) {
            f32x4 acc = {0.f, 0.f, 0.f, 0.f};
            acc = __builtin_amdgcn_mfma_f32_16x16x32_bf16(h[0], w2f[0][nb], acc, 0, 0, 0);
            acc = __builtin_amdgcn_mfma_f32_16x16x32_bf16(h[1], w2f[1][nb], acc, 0, 0, 0);
#pragma unroll
            for (int r = 0; r < 4; ++r) {
                int vrow = v0 + quad * 4 + r;
                if (vrow < n_nodes)
                    out[(size_t)vrow * D + nb * 16 + mr] = acc[r] + b2v[nb];
            }
        }
    }
}

// ---------------------------------------------------------------------------
extern "C" void kernel_launch(void* const* d_in, const int* in_sizes, int n_in,
                              void* d_out, int out_size, void* d_ws, size_t ws_size,
                              hipStream_t stream) {
    const float* x   = (const float*)d_in[0];
    const int*   ei  = (const int*)d_in[1];
    // d_in[2] = batch (unused)
    const float* mw1 = (const float*)d_in[3];
    const float* mb1 = (const float*)d_in[4];
    const float* mw2 = (const float*)d_in[5];
    const float* mb2 = (const float*)d_in[6];
    const float* ow1 = (const float*)d_in[7];
    const float* ob1 = (const float*)d_in[8];
    const float* ow2 = (const float*)d_in[9];
    const float* ob2 = (const float*)d_in[10];

    const int n_nodes = in_sizes[0] / D;        // 100000
    const int n_edges = in_sizes[1] / 2;        // 1000000
    const int* row = ei;                        // edge_index[0]
    const int* col = ei + n_edges;              // edge_index[1]

    const int nbuckets = (n_nodes + BW - 1) >> BSHIFT;   // 1563

    // ws layout: m | agg | region(tmp OR aggf) | gcur | wfrag
    __hip_bfloat16* m   = (__hip_bfloat16*)d_ws;               // [N*64] bf16
    __hip_bfloat16* agg = m + (size_t)n_nodes * D;             // [N*64] bf16 (fallback)
    unsigned int* tmp   = (unsigned int*)(agg + (size_t)n_nodes * D);
    const size_t region = (size_t)nbuckets * STRIDE * 4 > (size_t)n_nodes * D * 4
                        ? (size_t)nbuckets * STRIDE * 4 : (size_t)n_nodes * D * 4;
    int* gcur = (int*)((char*)tmp + region);                   // [nbuckets]
    short* wfrag = (short*)(((size_t)(char*)(gcur + nbuckets) + 15) & ~(size_t)15);
    float* aggf = (float*)tmp;                                 // fallback only
    const size_t need = (size_t)((char*)(wfrag + WFRAG_SHORTS) - (char*)d_ws);

    const int ntiles = (n_nodes + 15) / 16;
    int nmsg = (ntiles + 3) / 4;
    if (nmsg > 512) nmsg = 512;   // ~3 tiles/wave: amortize weight prologue

    const bool shape_ok = (n_nodes < (1 << 17)) && (nbuckets <= MAXB)
                       && (n_edges <= nbuckets * (STRIDE / 2));  // avg load << STRIDE

    if (ws_size >= need && shape_ok) {
        hipMemsetAsync(gcur, 0, (size_t)nbuckets * sizeof(int), stream);
        const int nbbin = 256;
        const int chunk = (n_edges + nbbin - 1) / nbbin;
        // merged msg+bin+prep: [0,nmsg)=msg, [nmsg,nmsg+nbbin)=bin, last=prep
        msg_bin_kernel<<<nmsg + nbbin + 1, 256, 0, stream>>>(
            x, mw1, mb1, mw2, mb2, m, n_nodes,
            row, col, gcur, tmp, n_edges, nbuckets, chunk, nmsg, nbbin,
            ow1, ow2, wfrag);
        bucket_gather_out_kernel<<<nbuckets, GT, 0, stream>>>(
            gcur, tmp, m, x, wfrag, ob1, ob2, (float*)d_out, n_nodes, nbuckets);
    } else {
        // fallback: msg only, then atomic scatter + cvt + out
        msg_bin_kernel<<<nmsg, 256, 0, stream>>>(
            x, mw1, mb1, mw2, mb2, m, n_nodes,
            row, col, gcur, tmp, n_edges, nbuckets, 0, nmsg, 0,
            ow1, ow2, (short*)agg /*unused*/);
        hipMemsetAsync(aggf, 0, (size_t)n_nodes * D * sizeof(float), stream);
        const int nwaves_s = (n_edges + 63) / 64;
        scatter_kernel<<<(nwaves_s + 3) / 4, 256, 0, stream>>>(row, col, m, aggf, n_edges);
        cvt_kernel<<<((n_nodes * D) + 255) / 256, 256, 0, stream>>>(aggf, agg, n_nodes * D);
        out_kernel<<<nmsg, 256, 0, stream>>>(x, agg, ow1, ob1, ow2, ob2,
                                             (float*)d_out, n_nodes);
    }
}

// Round 11
// 193.743 us; speedup vs baseline: 1.0146x; 1.0146x over previous
//
#include <hip/hip_runtime.h>
#include <hip/hip_bf16.h>

#define D 64
#define BSHIFT 6
#define BW (1 << BSHIFT)          // bucket width: 64 destination nodes
#define MAXB 2048                 // max buckets (LDS arrays in bin)
#define CAP 4096                  // max edges sorted per LDS round (16 KB)
#define STRIDE 2048               // fixed tmp slots per bucket (mean 640)
#define GT 256                    // gather block threads (4 waves)
#define SMEM_BYTES 27648          // msg_bin union: msg(27648) >= bin(24576)

typedef __attribute__((ext_vector_type(8))) short bf16x8;   // 8 bf16 in 4 VGPRs
typedef __attribute__((ext_vector_type(4))) float f32x4;

__device__ __forceinline__ short f2bf(float f) {
    __hip_bfloat16 h = __float2bfloat16(f);
    return *reinterpret_cast<short*>(&h);
}
// bf16 pair unpack: low/high 16 bits of a u32 -> float (bf16 = upper 16 of f32)
__device__ __forceinline__ float bf_lo(unsigned int u) {
    unsigned int b = u << 16; return __uint_as_float(b);
}
__device__ __forceinline__ float bf_hi(unsigned int u) {
    unsigned int b = u & 0xFFFF0000u; return __uint_as_float(b);
}

// ---------------------------------------------------------------------------
// Merged K1: blocks [0,nmsg) run the message MLP (verified R6 msg body);
// blocks [nmsg,..) run edge binning (verified R6 bin body).
// ---------------------------------------------------------------------------
__global__ __launch_bounds__(256) void msg_bin_kernel(
    const float* __restrict__ x,
    const float* __restrict__ w1, const float* __restrict__ b1,
    const float* __restrict__ w2, const float* __restrict__ b2,
    __hip_bfloat16* __restrict__ m, int n_nodes,
    const int* __restrict__ row, const int* __restrict__ col,
    int* __restrict__ gcur, unsigned int* __restrict__ tmp,
    int n_edges, int nbuckets, int chunk, int nmsg)
{
    __shared__ __align__(16) char smem[SMEM_BYTES];

    if ((int)blockIdx.x >= nmsg) {
        // ---------------- bin branch (R6 bin_kernel body) ----------------
        int* hist = (int*)smem;            // MAXB*4 = 8192
        int* base = hist + MAXB;           // 8192
        int* lcur = base + MAXB;           // 8192  (total 24576 <= SMEM)
        const int t = threadIdx.x;
        const int bb = blockIdx.x - nmsg;
        const int e0 = bb * chunk;
        const int e1 = min(e0 + chunk, n_edges);

        for (int i = t; i < nbuckets; i += 256) hist[i] = 0;
        __syncthreads();
        for (int e = e0 + t; e < e1; e += 256)
            atomicAdd(&hist[col[e] >> BSHIFT], 1);
        __syncthreads();
        for (int i = t; i < nbuckets; i += 256) {
            base[i] = hist[i] ? atomicAdd(&gcur[i], hist[i]) : 0;
            lcur[i] = 0;
        }
        __syncthreads();
        for (int e = e0 + t; e < e1; e += 256) {
            int c = col[e];
            int b = c >> BSHIFT;
            int loc = base[b] + atomicAdd(&lcur[b], 1);
            if (loc < STRIDE) {   // overflow clamp (memory safety)
                unsigned int val = ((unsigned int)(c & (BW - 1)) << 17)
                                 | (unsigned int)row[e];
                tmp[(size_t)b * STRIDE + loc] = val;
            }
        }
        return;
    }

    // ---------------- msg branch (R6 msg_kernel body) ----------------
    __hip_bfloat16* sHb = (__hip_bfloat16*)smem;        // 4*16*72*2 = 9216
    short* sW1 = (short*)(smem + 9216);                 // 64*72*2   = 9216
    short* sW2 = (short*)(smem + 18432);                // 64*72*2   = 9216

    const int tid  = threadIdx.x;
    const int lane = tid & 63;
    const int wslot = tid >> 6;
    const int mr   = lane & 15;
    const int quad = lane >> 4;

    for (int i = tid; i < 1024; i += 256) {
        const int r = i >> 4, c = (i & 15) * 4;
        float4 f = *(const float4*)&w1[i * 4];
        short* d = &sW1[r * 72 + c];
        d[0] = f2bf(f.x); d[1] = f2bf(f.y); d[2] = f2bf(f.z); d[3] = f2bf(f.w);
        float4 g = *(const float4*)&w2[i * 4];
        short* e = &sW2[r * 72 + c];
        e[0] = f2bf(g.x); e[1] = f2bf(g.y); e[2] = f2bf(g.z); e[3] = f2bf(g.w);
    }
    __syncthreads();

    bf16x8 w1f[2][4], w2f[2][4];
    float  b1v[4], b2v[4];
#pragma unroll
    for (int ks = 0; ks < 2; ++ks)
#pragma unroll
        for (int nb = 0; nb < 4; ++nb) {
            bf16x8 f1, f2;
#pragma unroll
            for (int j = 0; j < 8; ++j) {
                int k = ks * 32 + quad * 8 + j;
                f1[j] = sW1[k * 72 + nb * 16 + mr];
                f2[j] = sW2[k * 72 + nb * 16 + mr];
            }
            w1f[ks][nb] = f1;
            w2f[ks][nb] = f2;
        }
#pragma unroll
    for (int nb = 0; nb < 4; ++nb) {
        b1v[nb] = b1[nb * 16 + mr];
        b2v[nb] = b2[nb * 16 + mr];
    }

    __hip_bfloat16* Hw = sHb + wslot * (16 * 72);
    const int wid    = (blockIdx.x * 256 + threadIdx.x) >> 6;
    const int nwaves = nmsg * 4;
    const int ntiles = (n_nodes + 15) >> 4;

    for (int t = wid; t < ntiles; t += nwaves) {
        const int v0 = t * 16;
        int vr = v0 + mr;
        if (vr >= n_nodes) vr = n_nodes - 1;

        bf16x8 a[2];
#pragma unroll
        for (int ks = 0; ks < 2; ++ks) {
            const float* p = x + (size_t)vr * D + ks * 32 + quad * 8;
            float4 lo = *(const float4*)p;
            float4 hi = *(const float4*)(p + 4);
            bf16x8 f;
            f[0] = f2bf(lo.x); f[1] = f2bf(lo.y); f[2] = f2bf(lo.z); f[3] = f2bf(lo.w);
            f[4] = f2bf(hi.x); f[5] = f2bf(hi.y); f[6] = f2bf(hi.z); f[7] = f2bf(hi.w);
            a[ks] = f;
        }

#pragma unroll
        for (int nb = 0; nb < 4; ++nb) {
            f32x4 acc = {0.f, 0.f, 0.f, 0.f};
            acc = __builtin_amdgcn_mfma_f32_16x16x32_bf16(a[0], w1f[0][nb], acc, 0, 0, 0);
            acc = __builtin_amdgcn_mfma_f32_16x16x32_bf16(a[1], w1f[1][nb], acc, 0, 0, 0);
#pragma unroll
            for (int r = 0; r < 4; ++r) {
                float hv = fmaxf(acc[r] + b1v[nb], 0.f);
                Hw[(quad * 4 + r) * 72 + nb * 16 + mr] = __float2bfloat16(hv);
            }
        }

        bf16x8 h[2];
#pragma unroll
        for (int ks = 0; ks < 2; ++ks)
            h[ks] = *(const bf16x8*)&Hw[mr * 72 + ks * 32 + quad * 8];

#pragma unroll
        for (int nb = 0; nb < 4; ++nb) {
            f32x4 acc = {0.f, 0.f, 0.f, 0.f};
            acc = __builtin_amdgcn_mfma_f32_16x16x32_bf16(h[0], w2f[0][nb], acc, 0, 0, 0);
            acc = __builtin_amdgcn_mfma_f32_16x16x32_bf16(h[1], w2f[1][nb], acc, 0, 0, 0);
#pragma unroll
            for (int r = 0; r < 4; ++r)
                Hw[(quad * 4 + r) * 72 + nb * 16 + mr] =
                    __float2bfloat16(acc[r] + b2v[nb]);
        }

#pragma unroll
        for (int s = 0; s < 2; ++s) {
            const int rrow = s * 8 + (lane >> 3);
            const int cblk = (lane & 7) * 8;
            bf16x8 val = *(const bf16x8*)&Hw[rrow * 72 + cblk];
            const int vrow = v0 + rrow;
            if (vrow < n_nodes)
                *(bf16x8*)&m[(size_t)vrow * D + cblk] = val;
        }
    }
}

// ---------------------------------------------------------------------------
// K2: fused in-LDS CSR sort + register gather.
// R11 change vs R8: the gather load stream fetches uint2 (4 bf16) per lane,
// 16 lanes per m-row -> each load instruction covers 4 edges (4x fewer VMEM
// ops).  Quarter q of the wave owns edges j+4t+q; float4 partials per node;
// one 2-step shfl_xor cross-quarter reduce at the end.
// ---------------------------------------------------------------------------
__global__ __launch_bounds__(GT) void bucket_gather_kernel(
    const int* __restrict__ gcur, const unsigned int* __restrict__ tmp,
    const __hip_bfloat16* __restrict__ m, __hip_bfloat16* __restrict__ agg,
    int n_nodes, int nbuckets)
{
    __shared__ unsigned int sorted[CAP];   // 16 KB
    __shared__ int cnt[BW], off[BW], cur[BW];

    const int b    = blockIdx.x;
    const int t    = threadIdx.x;
    const int lane = t & 63;
    const int wv   = t >> 6;               // 0..3
    const int qtr  = lane >> 4;            // quarter 0..3 (edge subset)
    const int ql4  = (lane & 15) * 4;      // column offset (4 cols/lane)
    const int vbase = b << BSHIFT;
    const unsigned int* gtmp = tmp + (size_t)b * STRIDE;

    const int total = min(gcur[b], STRIDE);

    float4 acc4[16];                       // wave wv owns nodes wv + 4*i
#pragma unroll
    for (int i = 0; i < 16; ++i) acc4[i] = make_float4(0.f, 0.f, 0.f, 0.f);

    for (int r0 = 0; r0 < total; r0 += CAP) {
        const int r1 = min(r0 + CAP, total);

        if (t < BW) cnt[t] = 0;
        __syncthreads();

        for (int i = r0 + t; i < r1; i += GT)
            atomicAdd(&cnt[gtmp[i] >> 17], 1);
        __syncthreads();

        // 64-bin exclusive scan by wave 0: 1 bin/lane, 6 shfl_up steps.
        if (wv == 0) {
            int a0 = cnt[lane];
            int s0 = a0;
#pragma unroll
            for (int d = 1; d < 64; d <<= 1) {
                int u0 = __shfl_up(s0, d, 64);
                if (lane >= d) s0 += u0;
            }
            const int e0 = s0 - a0;                // exclusive prefix
            off[lane] = e0;
            cur[lane] = e0;
        }
        __syncthreads();

        for (int i = r0 + t; i < r1; i += GT) {
            unsigned int u = gtmp[i];
            int pos = atomicAdd(&cur[u >> 17], 1);
            sorted[pos] = u;
        }
        __syncthreads();

#pragma unroll
        for (int i = 0; i < 16; ++i) {
            const int n  = wv + (i << 2);
            const int o0 = off[n];
            const int c  = cnt[n];
            float4 s4 = make_float4(0.f, 0.f, 0.f, 0.f);
            for (int cs = 0; cs < c; cs += 64) {
                const int k = min(64, c - cs);
                unsigned int pv = 0;
                if (lane < k) pv = sorted[o0 + cs + lane];

                int j = 0;
                // 8 loads in flight = 32 edges (4 edges per load)
                for (; j + 32 <= k; j += 32) {
                    unsigned int ue[8];
                    uint2 dv[8];
#pragma unroll
                    for (int q = 0; q < 8; ++q)
                        ue[q] = __shfl(pv, j + q * 4 + qtr, 64);
#pragma unroll
                    for (int q = 0; q < 8; ++q)
                        dv[q] = *(const uint2*)&m[(size_t)(ue[q] & 0x1FFFFu) * D + ql4];
#pragma unroll
                    for (int q = 0; q < 8; ++q) {
                        s4.x += bf_lo(dv[q].x); s4.y += bf_hi(dv[q].x);
                        s4.z += bf_lo(dv[q].y); s4.w += bf_hi(dv[q].y);
                    }
                }
                // remainder: up to 16 edges per iter, guarded
                for (; j < k; j += 16) {
                    unsigned int ue[4];
                    int g[4];
#pragma unroll
                    for (int q = 0; q < 4; ++q) {
                        const int je = j + q * 4 + qtr;
                        ue[q] = __shfl(pv, je, 64);
                        g[q] = je < k;
                    }
#pragma unroll
                    for (int q = 0; q < 4; ++q) {
                        if (g[q]) {
                            uint2 d2 = *(const uint2*)&m[(size_t)(ue[q] & 0x1FFFFu) * D + ql4];
                            s4.x += bf_lo(d2.x); s4.y += bf_hi(d2.x);
                            s4.z += bf_lo(d2.y); s4.w += bf_hi(d2.y);
                        }
                    }
                }
            }
            acc4[i].x += s4.x; acc4[i].y += s4.y;
            acc4[i].z += s4.z; acc4[i].w += s4.w;
        }
        if (r1 < total) __syncthreads();   // only if another round follows
    }

    // cross-quarter reduce + write (quarter 0 lanes write 8B per node row)
#pragma unroll
    for (int i = 0; i < 16; ++i) {
        float4 s4 = acc4[i];
        s4.x += __shfl_xor(s4.x, 16, 64);
        s4.y += __shfl_xor(s4.y, 16, 64);
        s4.z += __shfl_xor(s4.z, 16, 64);
        s4.w += __shfl_xor(s4.w, 16, 64);
        s4.x += __shfl_xor(s4.x, 32, 64);
        s4.y += __shfl_xor(s4.y, 32, 64);
        s4.z += __shfl_xor(s4.z, 32, 64);
        s4.w += __shfl_xor(s4.w, 32, 64);
        const int v = vbase + wv + (i << 2);
        if (qtr == 0 && v < n_nodes) {
            uint2 pw;
            pw.x = ((unsigned int)(unsigned short)f2bf(s4.y) << 16)
                 | (unsigned short)f2bf(s4.x);
            pw.y = ((unsigned int)(unsigned short)f2bf(s4.w) << 16)
                 | (unsigned short)f2bf(s4.z);
            *(uint2*)&agg[(size_t)v * D + ql4] = pw;
        }
    }
}

// ---------------------------------------------------------------------------
// Fallback path (ws too small / shape out of range).
// ---------------------------------------------------------------------------
__global__ __launch_bounds__(256) void scatter_kernel(
    const int* __restrict__ row, const int* __restrict__ col,
    const __hip_bfloat16* __restrict__ m, float* __restrict__ aggf, int n_edges)
{
    const int lane = threadIdx.x & 63;
    const int wid  = (blockIdx.x * blockDim.x + threadIdx.x) >> 6;
    const int base = wid * 64;
    if (base >= n_edges) return;
    const int cnt = min(64, n_edges - base);

    int my_r = 0, my_c = 0;
    if (lane < cnt) { my_r = row[base + lane]; my_c = col[base + lane]; }

    for (int j = 0; j < cnt; ++j) {
        int r = __builtin_amdgcn_readlane(my_r, j);
        int c = __builtin_amdgcn_readlane(my_c, j);
        float v = (float)m[(size_t)r * D + lane];
        atomicAdd(&aggf[(size_t)c * D + lane], v);
    }
}

__global__ __launch_bounds__(256) void cvt_kernel(
    const float* __restrict__ aggf, __hip_bfloat16* __restrict__ agg, int n)
{
    int i = blockIdx.x * blockDim.x + threadIdx.x;
    if (i < n) agg[i] = __float2bfloat16(aggf[i]);
}

// ---------------------------------------------------------------------------
// K3: output MLP via MFMA.  out[v] = relu([x[v],agg[v]]@OW1 + ob1)@OW2 + ob2
// Weights staged once per block into LDS (verified R6 structure).
// ---------------------------------------------------------------------------
__global__ __launch_bounds__(256) void out_kernel(
    const float* __restrict__ x, const __hip_bfloat16* __restrict__ agg,
    const float* __restrict__ w1, const float* __restrict__ b1,
    const float* __restrict__ w2, const float* __restrict__ b2,
    float* __restrict__ out, int n_nodes)
{
    __shared__ __align__(16) __hip_bfloat16 sH[4][16 * 72];
    __shared__ short sW1[128 * 72];     // 18432 B
    __shared__ short sW2[64 * 72];      //  9216 B

    const int tid  = threadIdx.x;
    const int lane = tid & 63;
    const int wslot = tid >> 6;
    const int mr   = lane & 15;
    const int quad = lane >> 4;

    for (int i = tid; i < 2048; i += 256) {
        const int r = i >> 4, c = (i & 15) * 4;
        float4 f = *(const float4*)&w1[i * 4];
        short* d = &sW1[r * 72 + c];
        d[0] = f2bf(f.x); d[1] = f2bf(f.y); d[2] = f2bf(f.z); d[3] = f2bf(f.w);
    }
    for (int i = tid; i < 1024; i += 256) {
        const int r = i >> 4, c = (i & 15) * 4;
        float4 g = *(const float4*)&w2[i * 4];
        short* e = &sW2[r * 72 + c];
        e[0] = f2bf(g.x); e[1] = f2bf(g.y); e[2] = f2bf(g.z); e[3] = f2bf(g.w);
    }
    __syncthreads();

    bf16x8 w1f[4][4], w2f[2][4];
    float  b1v[4], b2v[4];
#pragma unroll
    for (int ks = 0; ks < 4; ++ks)
#pragma unroll
        for (int nb = 0; nb < 4; ++nb) {
            bf16x8 f;
#pragma unroll
            for (int j = 0; j < 8; ++j) {
                int k = ks * 32 + quad * 8 + j;
                f[j] = sW1[k * 72 + nb * 16 + mr];
            }
            w1f[ks][nb] = f;
        }
#pragma unroll
    for (int ks = 0; ks < 2; ++ks)
#pragma unroll
        for (int nb = 0; nb < 4; ++nb) {
            bf16x8 f;
#pragma unroll
            for (int j = 0; j < 8; ++j) {
                int k = ks * 32 + quad * 8 + j;
                f[j] = sW2[k * 72 + nb * 16 + mr];
            }
            w2f[ks][nb] = f;
        }
#pragma unroll
    for (int nb = 0; nb < 4; ++nb) {
        b1v[nb] = b1[nb * 16 + mr];
        b2v[nb] = b2[nb * 16 + mr];
    }

    __hip_bfloat16* Hw = sH[wslot];
    const int wid    = (blockIdx.x * blockDim.x + threadIdx.x) >> 6;
    const int nwaves = (gridDim.x * blockDim.x) >> 6;
    const int ntiles = (n_nodes + 15) >> 4;

    for (int t = wid; t < ntiles; t += nwaves) {
        const int v0 = t * 16;
        int vr = v0 + mr;
        if (vr >= n_nodes) vr = n_nodes - 1;

        bf16x8 a[4];
#pragma unroll
        for (int ks = 0; ks < 2; ++ks) {
            const float* p = x + (size_t)vr * D + ks * 32 + quad * 8;
            float4 lo = *(const float4*)p;
            float4 hi = *(const float4*)(p + 4);
            bf16x8 f;
            f[0] = f2bf(lo.x); f[1] = f2bf(lo.y); f[2] = f2bf(lo.z); f[3] = f2bf(lo.w);
            f[4] = f2bf(hi.x); f[5] = f2bf(hi.y); f[6] = f2bf(hi.z); f[7] = f2bf(hi.w);
            a[ks] = f;
        }
#pragma unroll
        for (int ks = 2; ks < 4; ++ks)
            a[ks] = *(const bf16x8*)&agg[(size_t)vr * D + (ks - 2) * 32 + quad * 8];

#pragma unroll
        for (int nb = 0; nb < 4; ++nb) {
            f32x4 acc = {0.f, 0.f, 0.f, 0.f};
#pragma unroll
            for (int ks = 0; ks < 4; ++ks)
                acc = __builtin_amdgcn_mfma_f32_16x16x32_bf16(a[ks], w1f[ks][nb], acc, 0, 0, 0);
#pragma unroll
            for (int r = 0; r < 4; ++r) {
                float hv = fmaxf(acc[r] + b1v[nb], 0.f);
                Hw[(quad * 4 + r) * 72 + nb * 16 + mr] = __float2bfloat16(hv);
            }
        }

        bf16x8 h[2];
#pragma unroll
        for (int ks = 0; ks < 2; ++ks)
            h[ks] = *(const bf16x8*)&Hw[mr * 72 + ks * 32 + quad * 8];

#pragma unroll
        for (int nb = 0; nb < 4; ++nb) {
            f32x4 acc = {0.f, 0.f, 0.f, 0.f};
            acc = __builtin_amdgcn_mfma_f32_16x16x32_bf16(h[0], w2f[0][nb], acc, 0, 0, 0);
            acc = __builtin_amdgcn_mfma_f32_16x16x32_bf16(h[1], w2f[1][nb], acc, 0, 0, 0);
#pragma unroll
            for (int r = 0; r < 4; ++r) {
                int vrow = v0 + quad * 4 + r;
                if (vrow < n_nodes)
                    out[(size_t)vrow * D + nb * 16 + mr] = acc[r] + b2v[nb];
            }
        }
    }
}

// ---------------------------------------------------------------------------
extern "C" void kernel_launch(void* const* d_in, const int* in_sizes, int n_in,
                              void* d_out, int out_size, void* d_ws, size_t ws_size,
                              hipStream_t stream) {
    const float* x   = (const float*)d_in[0];
    const int*   ei  = (const int*)d_in[1];
    // d_in[2] = batch (unused)
    const float* mw1 = (const float*)d_in[3];
    const float* mb1 = (const float*)d_in[4];
    const float* mw2 = (const float*)d_in[5];
    const float* mb2 = (const float*)d_in[6];
    const float* ow1 = (const float*)d_in[7];
    const float* ob1 = (const float*)d_in[8];
    const float* ow2 = (const float*)d_in[9];
    const float* ob2 = (const float*)d_in[10];

    const int n_nodes = in_sizes[0] / D;        // 100000
    const int n_edges = in_sizes[1] / 2;        // 1000000
    const int* row = ei;                        // edge_index[0]
    const int* col = ei + n_edges;              // edge_index[1]

    const int nbuckets = (n_nodes + BW - 1) >> BSHIFT;   // 1563

    // ws layout: m | agg | region(tmp OR aggf) | gcur
    __hip_bfloat16* m   = (__hip_bfloat16*)d_ws;               // [N*64] bf16
    __hip_bfloat16* agg = m + (size_t)n_nodes * D;             // [N*64] bf16
    unsigned int* tmp   = (unsigned int*)(agg + (size_t)n_nodes * D);
    const size_t region = (size_t)nbuckets * STRIDE * 4 > (size_t)n_nodes * D * 4
                        ? (size_t)nbuckets * STRIDE * 4 : (size_t)n_nodes * D * 4;
    int* gcur = (int*)((char*)tmp + region);                   // [nbuckets]
    float* aggf = (float*)tmp;                                 // fallback only
    const size_t need = (size_t)n_nodes * D * 4 + region + (size_t)nbuckets * 4;

    const int ntiles = (n_nodes + 15) / 16;
    int nmsg = (ntiles + 3) / 4;
    if (nmsg > 512) nmsg = 512;   // ~3 tiles/wave: amortize weight prologue

    const bool shape_ok = (n_nodes < (1 << 17)) && (nbuckets <= MAXB)
                       && (n_edges <= nbuckets * (STRIDE / 2));  // avg load << STRIDE

    if (ws_size >= need && shape_ok) {
        hipMemsetAsync(gcur, 0, (size_t)nbuckets * sizeof(int), stream);
        const int nbbin = 256;
        const int chunk = (n_edges + nbbin - 1) / nbbin;
        // merged msg+bin: blocks [0,nmsg) = msg, [nmsg, nmsg+nbbin) = bin
        msg_bin_kernel<<<nmsg + nbbin, 256, 0, stream>>>(
            x, mw1, mb1, mw2, mb2, m, n_nodes,
            row, col, gcur, tmp, n_edges, nbuckets, chunk, nmsg);
        bucket_gather_kernel<<<nbuckets, GT, 0, stream>>>(gcur, tmp, m, agg,
                                                          n_nodes, nbuckets);
    } else {
        // fallback: msg only (no bin blocks), then atomic scatter
        msg_bin_kernel<<<nmsg, 256, 0, stream>>>(
            x, mw1, mb1, mw2, mb2, m, n_nodes,
            row, col, gcur, tmp, n_edges, nbuckets, 0, nmsg);
        hipMemsetAsync(aggf, 0, (size_t)n_nodes * D * sizeof(float), stream);
        const int nwaves_s = (n_edges + 63) / 64;
        scatter_kernel<<<(nwaves_s + 3) / 4, 256, 0, stream>>>(row, col, m, aggf, n_edges);
        cvt_kernel<<<((n_nodes * D) + 255) / 256, 256, 0, stream>>>(aggf, agg, n_nodes * D);
    }

    out_kernel<<<nmsg, 256, 0, stream>>>(x, agg, ow1, ob1, ow2, ob2,
                                         (float*)d_out, n_nodes);
}

// Round 12
// 178.157 us; speedup vs baseline: 1.1033x; 1.0875x over previous
//
#include <hip/hip_runtime.h>
#include <hip/hip_bf16.h>

#define D 64
#define BSHIFT 6
#define BW (1 << BSHIFT)          // bucket width: 64 destination nodes
#define MAXB 2048                 // max buckets (LDS arrays in bin)
#define CAP 4096                  // max edges sorted per LDS round (16 KB)
#define STRIDE 2048               // fixed tmp slots per bucket (mean 640)
#define GT 256                    // gather block threads (4 waves)
#define SMEM_BYTES 27648          // msg_bin union: msg(27648) >= bin(24576)

typedef __attribute__((ext_vector_type(8))) short bf16x8;   // 8 bf16 in 4 VGPRs
typedef __attribute__((ext_vector_type(4))) float f32x4;

__device__ __forceinline__ short f2bf(float f) {
    __hip_bfloat16 h = __float2bfloat16(f);
    return *reinterpret_cast<short*>(&h);
}

// ---------------------------------------------------------------------------
// Merged K1: blocks [0,nmsg) run the message MLP (verified R6 msg body);
// blocks [nmsg,..) run edge binning (verified R6 bin body).
// ---------------------------------------------------------------------------
__global__ __launch_bounds__(256) void msg_bin_kernel(
    const float* __restrict__ x,
    const float* __restrict__ w1, const float* __restrict__ b1,
    const float* __restrict__ w2, const float* __restrict__ b2,
    __hip_bfloat16* __restrict__ m, int n_nodes,
    const int* __restrict__ row, const int* __restrict__ col,
    int* __restrict__ gcur, unsigned int* __restrict__ tmp,
    int n_edges, int nbuckets, int chunk, int nmsg)
{
    __shared__ __align__(16) char smem[SMEM_BYTES];

    if ((int)blockIdx.x >= nmsg) {
        // ---------------- bin branch (R6 bin_kernel body) ----------------
        int* hist = (int*)smem;            // MAXB*4 = 8192
        int* base = hist + MAXB;           // 8192
        int* lcur = base + MAXB;           // 8192  (total 24576 <= SMEM)
        const int t = threadIdx.x;
        const int bb = blockIdx.x - nmsg;
        const int e0 = bb * chunk;
        const int e1 = min(e0 + chunk, n_edges);

        for (int i = t; i < nbuckets; i += 256) hist[i] = 0;
        __syncthreads();
        for (int e = e0 + t; e < e1; e += 256)
            atomicAdd(&hist[col[e] >> BSHIFT], 1);
        __syncthreads();
        for (int i = t; i < nbuckets; i += 256) {
            base[i] = hist[i] ? atomicAdd(&gcur[i], hist[i]) : 0;
            lcur[i] = 0;
        }
        __syncthreads();
        for (int e = e0 + t; e < e1; e += 256) {
            int c = col[e];
            int b = c >> BSHIFT;
            int loc = base[b] + atomicAdd(&lcur[b], 1);
            if (loc < STRIDE) {   // overflow clamp (memory safety)
                unsigned int val = ((unsigned int)(c & (BW - 1)) << 17)
                                 | (unsigned int)row[e];
                tmp[(size_t)b * STRIDE + loc] = val;
            }
        }
        return;
    }

    // ---------------- msg branch (R6 msg_kernel body) ----------------
    __hip_bfloat16* sHb = (__hip_bfloat16*)smem;        // 4*16*72*2 = 9216
    short* sW1 = (short*)(smem + 9216);                 // 64*72*2   = 9216
    short* sW2 = (short*)(smem + 18432);                // 64*72*2   = 9216

    const int tid  = threadIdx.x;
    const int lane = tid & 63;
    const int wslot = tid >> 6;
    const int mr   = lane & 15;
    const int quad = lane >> 4;

    for (int i = tid; i < 1024; i += 256) {
        const int r = i >> 4, c = (i & 15) * 4;
        float4 f = *(const float4*)&w1[i * 4];
        short* d = &sW1[r * 72 + c];
        d[0] = f2bf(f.x); d[1] = f2bf(f.y); d[2] = f2bf(f.z); d[3] = f2bf(f.w);
        float4 g = *(const float4*)&w2[i * 4];
        short* e = &sW2[r * 72 + c];
        e[0] = f2bf(g.x); e[1] = f2bf(g.y); e[2] = f2bf(g.z); e[3] = f2bf(g.w);
    }
    __syncthreads();

    bf16x8 w1f[2][4], w2f[2][4];
    float  b1v[4], b2v[4];
#pragma unroll
    for (int ks = 0; ks < 2; ++ks)
#pragma unroll
        for (int nb = 0; nb < 4; ++nb) {
            bf16x8 f1, f2;
#pragma unroll
            for (int j = 0; j < 8; ++j) {
                int k = ks * 32 + quad * 8 + j;
                f1[j] = sW1[k * 72 + nb * 16 + mr];
                f2[j] = sW2[k * 72 + nb * 16 + mr];
            }
            w1f[ks][nb] = f1;
            w2f[ks][nb] = f2;
        }
#pragma unroll
    for (int nb = 0; nb < 4; ++nb) {
        b1v[nb] = b1[nb * 16 + mr];
        b2v[nb] = b2[nb * 16 + mr];
    }

    __hip_bfloat16* Hw = sHb + wslot * (16 * 72);
    const int wid    = (blockIdx.x * 256 + threadIdx.x) >> 6;
    const int nwaves = nmsg * 4;
    const int ntiles = (n_nodes + 15) >> 4;

    for (int t = wid; t < ntiles; t += nwaves) {
        const int v0 = t * 16;
        int vr = v0 + mr;
        if (vr >= n_nodes) vr = n_nodes - 1;

        bf16x8 a[2];
#pragma unroll
        for (int ks = 0; ks < 2; ++ks) {
            const float* p = x + (size_t)vr * D + ks * 32 + quad * 8;
            float4 lo = *(const float4*)p;
            float4 hi = *(const float4*)(p + 4);
            bf16x8 f;
            f[0] = f2bf(lo.x); f[1] = f2bf(lo.y); f[2] = f2bf(lo.z); f[3] = f2bf(lo.w);
            f[4] = f2bf(hi.x); f[5] = f2bf(hi.y); f[6] = f2bf(hi.z); f[7] = f2bf(hi.w);
            a[ks] = f;
        }

#pragma unroll
        for (int nb = 0; nb < 4; ++nb) {
            f32x4 acc = {0.f, 0.f, 0.f, 0.f};
            acc = __builtin_amdgcn_mfma_f32_16x16x32_bf16(a[0], w1f[0][nb], acc, 0, 0, 0);
            acc = __builtin_amdgcn_mfma_f32_16x16x32_bf16(a[1], w1f[1][nb], acc, 0, 0, 0);
#pragma unroll
            for (int r = 0; r < 4; ++r) {
                float hv = fmaxf(acc[r] + b1v[nb], 0.f);
                Hw[(quad * 4 + r) * 72 + nb * 16 + mr] = __float2bfloat16(hv);
            }
        }

        bf16x8 h[2];
#pragma unroll
        for (int ks = 0; ks < 2; ++ks)
            h[ks] = *(const bf16x8*)&Hw[mr * 72 + ks * 32 + quad * 8];

#pragma unroll
        for (int nb = 0; nb < 4; ++nb) {
            f32x4 acc = {0.f, 0.f, 0.f, 0.f};
            acc = __builtin_amdgcn_mfma_f32_16x16x32_bf16(h[0], w2f[0][nb], acc, 0, 0, 0);
            acc = __builtin_amdgcn_mfma_f32_16x16x32_bf16(h[1], w2f[1][nb], acc, 0, 0, 0);
#pragma unroll
            for (int r = 0; r < 4; ++r)
                Hw[(quad * 4 + r) * 72 + nb * 16 + mr] =
                    __float2bfloat16(acc[r] + b2v[nb]);
        }

#pragma unroll
        for (int s = 0; s < 2; ++s) {
            const int rrow = s * 8 + (lane >> 3);
            const int cblk = (lane & 7) * 8;
            bf16x8 val = *(const bf16x8*)&Hw[rrow * 72 + cblk];
            const int vrow = v0 + rrow;
            if (vrow < n_nodes)
                *(bf16x8*)&m[(size_t)vrow * D + cblk] = val;
        }
    }
}

// ---------------------------------------------------------------------------
// K2: fused in-LDS CSR sort + register gather.
// R12 change vs R9: the scalar per-edge tail loop is folded into the 8-deep
// batch via CLAMPED wave-uniform readlane indices (min(j+q,k-1); all SGPR
// operands, no bpermute) + uniform-predicate masked adds.  Every batch issues
// 8 parallel loads regardless of k mod 8 -> no serial full-latency tails.
// ---------------------------------------------------------------------------
__global__ __launch_bounds__(GT) void bucket_gather_kernel(
    const int* __restrict__ gcur, const unsigned int* __restrict__ tmp,
    const __hip_bfloat16* __restrict__ m, __hip_bfloat16* __restrict__ agg,
    int n_nodes, int nbuckets)
{
    __shared__ unsigned int sorted[CAP];   // 16 KB
    __shared__ int cnt[BW], off[BW], cur[BW];

    const int b    = blockIdx.x;
    const int t    = threadIdx.x;
    const int lane = t & 63;
    const int wv   = t >> 6;               // 0..3
    const int vbase = b << BSHIFT;
    const unsigned int* gtmp = tmp + (size_t)b * STRIDE;

    const int total = min(gcur[b], STRIDE);

    float acc[16];                         // wave wv owns nodes wv + 4*i
#pragma unroll
    for (int i = 0; i < 16; ++i) acc[i] = 0.f;

    for (int r0 = 0; r0 < total; r0 += CAP) {
        const int r1 = min(r0 + CAP, total);

        if (t < BW) cnt[t] = 0;
        __syncthreads();

        for (int i = r0 + t; i < r1; i += GT)
            atomicAdd(&cnt[gtmp[i] >> 17], 1);
        __syncthreads();

        // 64-bin exclusive scan by wave 0: 1 bin/lane, 6 shfl_up steps.
        if (wv == 0) {
            int a0 = cnt[lane];
            int s0 = a0;
#pragma unroll
            for (int d = 1; d < 64; d <<= 1) {
                int u0 = __shfl_up(s0, d, 64);
                if (lane >= d) s0 += u0;
            }
            const int e0 = s0 - a0;                // exclusive prefix
            off[lane] = e0;
            cur[lane] = e0;
        }
        __syncthreads();

        for (int i = r0 + t; i < r1; i += GT) {
            unsigned int u = gtmp[i];
            int pos = atomicAdd(&cur[u >> 17], 1);
            sorted[pos] = u;
        }
        __syncthreads();

#pragma unroll
        for (int i = 0; i < 16; ++i) {
            const int n  = wv + (i << 2);
            const int o0 = off[n];
            const int c  = cnt[n];
            float s = 0.f;
            for (int cs = 0; cs < c; cs += 64) {
                const int k = min(64, c - cs);
                unsigned int pv = 0;
                if (lane < k) pv = sorted[o0 + cs + lane];

                for (int j = 0; j < k; j += 8) {
                    unsigned int u[8];
                    float v[8];
#pragma unroll
                    for (int q = 0; q < 8; ++q) {
                        int je = j + q;              // wave-uniform
                        if (je > k - 1) je = k - 1;  // clamp (uniform)
                        u[q] = __builtin_amdgcn_readlane(pv, je);
                    }
#pragma unroll
                    for (int q = 0; q < 8; ++q)
                        v[q] = (float)m[(size_t)(u[q] & 0x1FFFFu) * D + lane];
#pragma unroll
                    for (int q = 0; q < 8; ++q)
                        s += (j + q < k) ? v[q] : 0.f;   // uniform predicate
                }
            }
            acc[i] += s;
        }
        if (r1 < total) __syncthreads();   // only if another round follows
    }

#pragma unroll
    for (int i = 0; i < 16; ++i) {
        const int v = vbase + wv + (i << 2);
        if (v < n_nodes)
            agg[(size_t)v * D + lane] = __float2bfloat16(acc[i]);
    }
}

// ---------------------------------------------------------------------------
// Fallback path (ws too small / shape out of range).
// ---------------------------------------------------------------------------
__global__ __launch_bounds__(256) void scatter_kernel(
    const int* __restrict__ row, const int* __restrict__ col,
    const __hip_bfloat16* __restrict__ m, float* __restrict__ aggf, int n_edges)
{
    const int lane = threadIdx.x & 63;
    const int wid  = (blockIdx.x * blockDim.x + threadIdx.x) >> 6;
    const int base = wid * 64;
    if (base >= n_edges) return;
    const int cnt = min(64, n_edges - base);

    int my_r = 0, my_c = 0;
    if (lane < cnt) { my_r = row[base + lane]; my_c = col[base + lane]; }

    for (int j = 0; j < cnt; ++j) {
        int r = __builtin_amdgcn_readlane(my_r, j);
        int c = __builtin_amdgcn_readlane(my_c, j);
        float v = (float)m[(size_t)r * D + lane];
        atomicAdd(&aggf[(size_t)c * D + lane], v);
    }
}

__global__ __launch_bounds__(256) void cvt_kernel(
    const float* __restrict__ aggf, __hip_bfloat16* __restrict__ agg, int n)
{
    int i = blockIdx.x * blockDim.x + threadIdx.x;
    if (i < n) agg[i] = __float2bfloat16(aggf[i]);
}

// ---------------------------------------------------------------------------
// K3: output MLP via MFMA.  out[v] = relu([x[v],agg[v]]@OW1 + ob1)@OW2 + ob2
// Weights staged once per block into LDS (verified R6 structure).
// ---------------------------------------------------------------------------
__global__ __launch_bounds__(256) void out_kernel(
    const float* __restrict__ x, const __hip_bfloat16* __restrict__ agg,
    const float* __restrict__ w1, const float* __restrict__ b1,
    const float* __restrict__ w2, const float* __restrict__ b2,
    float* __restrict__ out, int n_nodes)
{
    __shared__ __align__(16) __hip_bfloat16 sH[4][16 * 72];
    __shared__ short sW1[128 * 72];     // 18432 B
    __shared__ short sW2[64 * 72];      //  9216 B

    const int tid  = threadIdx.x;
    const int lane = tid & 63;
    const int wslot = tid >> 6;
    const int mr   = lane & 15;
    const int quad = lane >> 4;

    for (int i = tid; i < 2048; i += 256) {
        const int r = i >> 4, c = (i & 15) * 4;
        float4 f = *(const float4*)&w1[i * 4];
        short* d = &sW1[r * 72 + c];
        d[0] = f2bf(f.x); d[1] = f2bf(f.y); d[2] = f2bf(f.z); d[3] = f2bf(f.w);
    }
    for (int i = tid; i < 1024; i += 256) {
        const int r = i >> 4, c = (i & 15) * 4;
        float4 g = *(const float4*)&w2[i * 4];
        short* e = &sW2[r * 72 + c];
        e[0] = f2bf(g.x); e[1] = f2bf(g.y); e[2] = f2bf(g.z); e[3] = f2bf(g.w);
    }
    __syncthreads();

    bf16x8 w1f[4][4], w2f[2][4];
    float  b1v[4], b2v[4];
#pragma unroll
    for (int ks = 0; ks < 4; ++ks)
#pragma unroll
        for (int nb = 0; nb < 4; ++nb) {
            bf16x8 f;
#pragma unroll
            for (int j = 0; j < 8; ++j) {
                int k = ks * 32 + quad * 8 + j;
                f[j] = sW1[k * 72 + nb * 16 + mr];
            }
            w1f[ks][nb] = f;
        }
#pragma unroll
    for (int ks = 0; ks < 2; ++ks)
#pragma unroll
        for (int nb = 0; nb < 4; ++nb) {
            bf16x8 f;
#pragma unroll
            for (int j = 0; j < 8; ++j) {
                int k = ks * 32 + quad * 8 + j;
                f[j] = sW2[k * 72 + nb * 16 + mr];
            }
            w2f[ks][nb] = f;
        }
#pragma unroll
    for (int nb = 0; nb < 4; ++nb) {
        b1v[nb] = b1[nb * 16 + mr];
        b2v[nb] = b2[nb * 16 + mr];
    }

    __hip_bfloat16* Hw = sH[wslot];
    const int wid    = (blockIdx.x * blockDim.x + threadIdx.x) >> 6;
    const int nwaves = (gridDim.x * blockDim.x) >> 6;
    const int ntiles = (n_nodes + 15) >> 4;

    for (int t = wid; t < ntiles; t += nwaves) {
        const int v0 = t * 16;
        int vr = v0 + mr;
        if (vr >= n_nodes) vr = n_nodes - 1;

        bf16x8 a[4];
#pragma unroll
        for (int ks = 0; ks < 2; ++ks) {
            const float* p = x + (size_t)vr * D + ks * 32 + quad * 8;
            float4 lo = *(const float4*)p;
            float4 hi = *(const float4*)(p + 4);
            bf16x8 f;
            f[0] = f2bf(lo.x); f[1] = f2bf(lo.y); f[2] = f2bf(lo.z); f[3] = f2bf(lo.w);
            f[4] = f2bf(hi.x); f[5] = f2bf(hi.y); f[6] = f2bf(hi.z); f[7] = f2bf(hi.w);
            a[ks] = f;
        }
#pragma unroll
        for (int ks = 2; ks < 4; ++ks)
            a[ks] = *(const bf16x8*)&agg[(size_t)vr * D + (ks - 2) * 32 + quad * 8];

#pragma unroll
        for (int nb = 0; nb < 4; ++nb) {
            f32x4 acc = {0.f, 0.f, 0.f, 0.f};
#pragma unroll
            for (int ks = 0; ks < 4; ++ks)
                acc = __builtin_amdgcn_mfma_f32_16x16x32_bf16(a[ks], w1f[ks][nb], acc, 0, 0, 0);
#pragma unroll
            for (int r = 0; r < 4; ++r) {
                float hv = fmaxf(acc[r] + b1v[nb], 0.f);
                Hw[(quad * 4 + r) * 72 + nb * 16 + mr] = __float2bfloat16(hv);
            }
        }

        bf16x8 h[2];
#pragma unroll
        for (int ks = 0; ks < 2; ++ks)
            h[ks] = *(const bf16x8*)&Hw[mr * 72 + ks * 32 + quad * 8];

#pragma unroll
        for (int nb = 0; nb < 4; ++nb) {
            f32x4 acc = {0.f, 0.f, 0.f, 0.f};
            acc = __builtin_amdgcn_mfma_f32_16x16x32_bf16(h[0], w2f[0][nb], acc, 0, 0, 0);
            acc = __builtin_amdgcn_mfma_f32_16x16x32_bf16(h[1], w2f[1][nb], acc, 0, 0, 0);
#pragma unroll
            for (int r = 0; r < 4; ++r) {
                int vrow = v0 + quad * 4 + r;
                if (vrow < n_nodes)
                    out[(size_t)vrow * D + nb * 16 + mr] = acc[r] + b2v[nb];
            }
        }
    }
}

// ---------------------------------------------------------------------------
extern "C" void kernel_launch(void* const* d_in, const int* in_sizes, int n_in,
                              void* d_out, int out_size, void* d_ws, size_t ws_size,
                              hipStream_t stream) {
    const float* x   = (const float*)d_in[0];
    const int*   ei  = (const int*)d_in[1];
    // d_in[2] = batch (unused)
    const float* mw1 = (const float*)d_in[3];
    const float* mb1 = (const float*)d_in[4];
    const float* mw2 = (const float*)d_in[5];
    const float* mb2 = (const float*)d_in[6];
    const float* ow1 = (const float*)d_in[7];
    const float* ob1 = (const float*)d_in[8];
    const float* ow2 = (const float*)d_in[9];
    const float* ob2 = (const float*)d_in[10];

    const int n_nodes = in_sizes[0] / D;        // 100000
    const int n_edges = in_sizes[1] / 2;        // 1000000
    const int* row = ei;                        // edge_index[0]
    const int* col = ei + n_edges;              // edge_index[1]

    const int nbuckets = (n_nodes + BW - 1) >> BSHIFT;   // 1563

    // ws layout: m | agg | region(tmp OR aggf) | gcur
    __hip_bfloat16* m   = (__hip_bfloat16*)d_ws;               // [N*64] bf16
    __hip_bfloat16* agg = m + (size_t)n_nodes * D;             // [N*64] bf16
    unsigned int* tmp   = (unsigned int*)(agg + (size_t)n_nodes * D);
    const size_t region = (size_t)nbuckets * STRIDE * 4 > (size_t)n_nodes * D * 4
                        ? (size_t)nbuckets * STRIDE * 4 : (size_t)n_nodes * D * 4;
    int* gcur = (int*)((char*)tmp + region);                   // [nbuckets]
    float* aggf = (float*)tmp;                                 // fallback only
    const size_t need = (size_t)n_nodes * D * 4 + region + (size_t)nbuckets * 4;

    const int ntiles = (n_nodes + 15) / 16;
    int nmsg = (ntiles + 3) / 4;
    if (nmsg > 512) nmsg = 512;   // ~3 tiles/wave: amortize weight prologue

    const bool shape_ok = (n_nodes < (1 << 17)) && (nbuckets <= MAXB)
                       && (n_edges <= nbuckets * (STRIDE / 2));  // avg load << STRIDE

    if (ws_size >= need && shape_ok) {
        hipMemsetAsync(gcur, 0, (size_t)nbuckets * sizeof(int), stream);
        const int nbbin = 256;
        const int chunk = (n_edges + nbbin - 1) / nbbin;
        // merged msg+bin: blocks [0,nmsg) = msg, [nmsg, nmsg+nbbin) = bin
        msg_bin_kernel<<<nmsg + nbbin, 256, 0, stream>>>(
            x, mw1, mb1, mw2, mb2, m, n_nodes,
            row, col, gcur, tmp, n_edges, nbuckets, chunk, nmsg);
        bucket_gather_kernel<<<nbuckets, GT, 0, stream>>>(gcur, tmp, m, agg,
                                                          n_nodes, nbuckets);
    } else {
        // fallback: msg only (no bin blocks), then atomic scatter
        msg_bin_kernel<<<nmsg, 256, 0, stream>>>(
            x, mw1, mb1, mw2, mb2, m, n_nodes,
            row, col, gcur, tmp, n_edges, nbuckets, 0, nmsg);
        hipMemsetAsync(aggf, 0, (size_t)n_nodes * D * sizeof(float), stream);
        const int nwaves_s = (n_edges + 63) / 64;
        scatter_kernel<<<(nwaves_s + 3) / 4, 256, 0, stream>>>(row, col, m, aggf, n_edges);
        cvt_kernel<<<((n_nodes * D) + 255) / 256, 256, 0, stream>>>(aggf, agg, n_nodes * D);
    }

    out_kernel<<<nmsg, 256, 0, stream>>>(x, agg, ow1, ob1, ow2, ob2,
                                         (float*)d_out, n_nodes);
}